// Round 6
// baseline (2221.936 us; speedup 1.0000x reference)
//
#include <hip/hip_runtime.h>

typedef __bf16 bf16;
typedef __bf16 bf16x4 __attribute__((ext_vector_type(4)));
typedef __bf16 bf16x8 __attribute__((ext_vector_type(8)));
typedef float  f32x4  __attribute__((ext_vector_type(4)));

#define BM 128
#define BN 128
#define BKT 64
#define LDT 72   // legacy gram LDS row stride

#ifndef __has_builtin
#define __has_builtin(x) 0
#endif

// 16B direct global->LDS: wave-uniform LDS base, per-lane global src (lane*16B dest).
#if __has_builtin(__builtin_amdgcn_global_load_lds)
#define GLL16(srcp, basep) \
  __builtin_amdgcn_global_load_lds( \
      (const __attribute__((address_space(1))) unsigned int*)(srcp), \
      (__attribute__((address_space(3))) unsigned int*)(basep), 16, 0, 0)
#else
#define GLL16(srcp, basep) \
  (((bf16x8*)(basep))[lane] = *(const bf16x8*)(srcp))
#endif

// AMODE: 0 = gather concat [obj[s] | pred | obj[o]] (f32 -> bf16, VGPR path)
//        1 = bn_lrelu(scale*x+shift) applied to bf16 source
//        2 = f32 source * invcnt[row]
//        3 = plain bf16 copy (global_load_lds path)
//        5 = gather concat from PRE-CONVERTED bf16 objB/predB (global_load_lds path;
//            objB passed via `obj`, predB via `pred`)
// EPI:   0 = store bf16 + column stats atomics
//        2 = bn_lrelu then atomic scatter (tier-3 fallback)
//        3 = store f32 + column stats atomics
//        5 = bn_lrelu; cols<512 -> buf[(row-rbase)*1024+n1] bf16,
//            512..639 -> outF (new_p f32), >=640 -> buf[..+n1-128] bf16
template<int AMODE, int EPI>
__global__ __launch_bounds__(256) void gemm_k(
    const bf16* __restrict__ Abf, const float* __restrict__ Af32,
    const float* __restrict__ obj, const float* __restrict__ pred,
    const int* __restrict__ edges, const float* __restrict__ invcnt,
    const float* __restrict__ scale, const float* __restrict__ shift,
    const float* __restrict__ oscale, const float* __restrict__ oshift,
    const bf16* __restrict__ WT,      // (N,K) bf16, pre-transposed
    bf16* __restrict__ outB, float* __restrict__ outF,
    float* __restrict__ pooled, float* __restrict__ gsum, float* __restrict__ gsq,
    int M, int N, int K, int rbase)
{
  __shared__ __align__(16) bf16 As[BM * 64];
  __shared__ __align__(16) bf16 Bs[BN * 64];
  __shared__ float sc_sh[(AMODE == 1) ? 512 : 1];
  __shared__ float sh_sh[(AMODE == 1) ? 512 : 1];
  __shared__ float osc[(EPI == 2 || EPI == 5) ? BN : 1];
  __shared__ float osh[(EPI == 2 || EPI == 5) ? BN : 1];
  __shared__ int eS[(AMODE == 0 || AMODE == 5 || EPI == 2) ? BM : 1];
  __shared__ int eO[(AMODE == 0 || AMODE == 5 || EPI == 2) ? BM : 1];

  const int tid = threadIdx.x;

  // ---- XCD-aligned swizzle (bijective; tail handled linearly)
  int bx = blockIdx.x, by = blockIdx.y;
  {
    const int NX = gridDim.x, NY = gridDim.y;
    int L = by * NX + bx;
    int bpg = NX * 8;
    int nFull = NY >> 3;
    int Lfull = nFull * bpg;
    if (L < Lfull) {
      int g = L / bpg, w2 = L - g * bpg;
      by = (g << 3) + (w2 & 7);
      bx = w2 >> 3;
    } else {
      int r2 = L - Lfull;
      int q = r2 / NX;
      by = (nFull << 3) + q;
      bx = r2 - q * NX;
    }
  }
  const int m0 = rbase + by * BM;
  const int n0 = bx * BN;

  const int lane = tid & 63;
  const int w = tid >> 6;
  const int wm = (w >> 1) * 64;
  const int wn = (w & 1) * 64;
  const int l15 = lane & 15;
  const int quad = lane >> 4;

  if (AMODE == 1) {
    for (int c = tid; c < K; c += 256) { sc_sh[c] = scale[c]; sh_sh[c] = shift[c]; }
  }
  if (EPI == 2 || EPI == 5) {
    if (tid < BN) { osc[tid] = oscale[n0 + tid]; osh[tid] = oshift[n0 + tid]; }
  }
  if (AMODE == 0 || AMODE == 5 || EPI == 2) {
    if (tid < BM) {
      int r = m0 + tid; if (r >= M) r = M - 1;
      eS[tid] = edges[2 * r];
      eO[tid] = edges[2 * r + 1];
    }
  }
  __syncthreads();

  f32x4 acc[4][4];
  #pragma unroll
  for (int i = 0; i < 4; ++i)
    #pragma unroll
    for (int j = 0; j < 4; ++j)
      acc[i][j] = (f32x4){0.f, 0.f, 0.f, 0.f};

  const int rsub = lane >> 3;   // 0..7: row within 8-row block
  const int cch  = lane & 7;    // 16B chunk within row

  for (int k0 = 0; k0 < K; k0 += BKT) {
    // ---- stage B^T tile: 128 rows x 64 k, direct-to-LDS, source-swizzled
    #pragma unroll
    for (int it = 0; it < 4; ++it) {
      int blk = it * 4 + w;
      int r = blk * 8 + rsub;
      int cs = cch ^ (r & 7);
      const bf16* src = WT + (size_t)(n0 + r) * K + k0 + cs * 8;
      GLL16(src, &Bs[blk * 512]);
    }
    // ---- stage A tile
    if (AMODE == 3) {
      #pragma unroll
      for (int it = 0; it < 4; ++it) {
        int blk = it * 4 + w;
        int r = blk * 8 + rsub;
        int row = m0 + r; if (row >= M) row = M - 1;
        int cs = cch ^ (r & 7);
        const bf16* src = Abf + (size_t)row * K + k0 + cs * 8;
        GLL16(src, &As[blk * 512]);
      }
    } else if (AMODE == 5) {
      const bf16* objB  = (const bf16*)obj;
      const bf16* predB = (const bf16*)pred;
      #pragma unroll
      for (int it = 0; it < 4; ++it) {
        int blk = it * 4 + w;
        int r = blk * 8 + rsub;
        int row = m0 + r; if (row >= M) row = M - 1;
        int cs = cch ^ (r & 7);
        int k = k0 + cs * 8;
        const bf16* src;
        if (k0 < 128)      src = objB  + (size_t)eS[r] * 128 + k;
        else if (k0 < 256) src = predB + (size_t)row * 128 + (k - 128);
        else               src = objB  + (size_t)eO[r] * 128 + (k - 256);
        GLL16(src, &As[blk * 512]);
      }
    } else if (AMODE == 1) {
      int idx = tid;
      #pragma unroll
      for (int it = 0; it < 4; ++it, idx += 256) {
        int r = idx >> 3, ch = idx & 7;
        int row = m0 + r; if (row >= M) row = M - 1;
        bf16x8 v = *reinterpret_cast<const bf16x8*>(Abf + (size_t)row * K + k0 + ch * 8);
        bf16x8 o;
        #pragma unroll
        for (int e = 0; e < 8; ++e) {
          int c = k0 + ch * 8 + e;
          float f = sc_sh[c] * (float)v[e] + sh_sh[c];
          f = f >= 0.f ? f : 0.2f * f;
          o[e] = (bf16)f;
        }
        *reinterpret_cast<bf16x8*>(&As[r * 64 + ((ch ^ (r & 7)) << 3)]) = o;
      }
    } else {
      int idx = tid;
      #pragma unroll
      for (int it = 0; it < 8; ++it, idx += 256) {
        int r = idx >> 4, c4 = (idx & 15) << 2;
        int row = m0 + r; if (row >= M) row = M - 1;
        const float* src;
        float mul = 1.f;
        if (AMODE == 0) {
          int k = k0 + c4;
          if (k < 128)      src = obj  + (size_t)eS[r] * 128 + k;
          else if (k < 256) src = pred + (size_t)row * 128 + (k - 128);
          else              src = obj  + (size_t)eO[r] * 128 + (k - 256);
        } else {
          src = Af32 + (size_t)row * K + k0 + c4;
          mul = invcnt[row];
        }
        float4 v = *reinterpret_cast<const float4*>(src);
        bf16x4 o;
        o[0] = (bf16)(v.x * mul); o[1] = (bf16)(v.y * mul);
        o[2] = (bf16)(v.z * mul); o[3] = (bf16)(v.w * mul);
        int ch = c4 >> 3;
        int half = (c4 >> 2) & 1;
        *reinterpret_cast<bf16x4*>(&As[r * 64 + ((ch ^ (r & 7)) << 3) + (half << 2)]) = o;
      }
    }
    __syncthreads();
    #pragma unroll
    for (int kk = 0; kk < BKT; kk += 32) {
      bf16x8 af[4], bfv[4];
      #pragma unroll
      for (int i = 0; i < 4; ++i) {
        int r = wm + i * 16 + l15;
        int ci = (kk >> 3) + quad;
        af[i] = *reinterpret_cast<const bf16x8*>(&As[r * 64 + ((ci ^ (r & 7)) << 3)]);
      }
      #pragma unroll
      for (int j = 0; j < 4; ++j) {
        int r = wn + j * 16 + l15;
        int ci = (kk >> 3) + quad;
        bfv[j] = *reinterpret_cast<const bf16x8*>(&Bs[r * 64 + ((ci ^ (r & 7)) << 3)]);
      }
      #pragma unroll
      for (int i = 0; i < 4; ++i)
        #pragma unroll
        for (int j = 0; j < 4; ++j)
          acc[i][j] = __builtin_amdgcn_mfma_f32_16x16x32_bf16(af[i], bfv[j], acc[i][j], 0, 0, 0);
    }
    __syncthreads();
  }

  if (EPI == 2) {
    #pragma unroll
    for (int i = 0; i < 4; ++i) {
      #pragma unroll
      for (int r = 0; r < 4; ++r) {
        int lrow = wm + i * 16 + quad * 4 + r;
        int row = m0 + lrow;
        if (row >= M) continue;
        #pragma unroll
        for (int j = 0; j < 4; ++j) {
          int cl = wn + j * 16 + l15;
          int n1 = n0 + cl;
          float v = osc[cl] * acc[i][j][r] + osh[cl];
          v = v >= 0.f ? v : 0.2f * v;
          if (n1 < 512)      atomicAdd(&pooled[(size_t)eS[lrow] * 512 + n1], v);
          else if (n1 < 640) outF[(size_t)row * 128 + (n1 - 512)] = v;
          else               atomicAdd(&pooled[(size_t)eO[lrow] * 512 + (n1 - 640)], v);
        }
      }
    }
  } else if (EPI == 5) {
    #pragma unroll
    for (int i = 0; i < 4; ++i) {
      #pragma unroll
      for (int r = 0; r < 4; ++r) {
        int lrow = wm + i * 16 + quad * 4 + r;
        int row = m0 + lrow;
        if (row >= M) continue;
        #pragma unroll
        for (int j = 0; j < 4; ++j) {
          int cl = wn + j * 16 + l15;
          int n1 = n0 + cl;
          float v = osc[cl] * acc[i][j][r] + osh[cl];
          v = v >= 0.f ? v : 0.2f * v;
          if (n1 < 512)      outB[(size_t)(row - rbase) * 1024 + n1] = (bf16)v;
          else if (n1 < 640) outF[(size_t)row * 128 + (n1 - 512)] = v;
          else               outB[(size_t)(row - rbase) * 1024 + (n1 - 128)] = (bf16)v;
        }
      }
    }
  } else {
    #pragma unroll
    for (int j = 0; j < 4; ++j) {
      float s = 0.f, q = 0.f;
      #pragma unroll
      for (int i = 0; i < 4; ++i) {
        #pragma unroll
        for (int r = 0; r < 4; ++r) {
          int row = m0 + wm + i * 16 + quad * 4 + r;
          if (row >= M) continue;
          float v = acc[i][j][r];
          s += v; q += v * v;
          int col = n0 + wn + j * 16 + l15;
          if (EPI == 0) outB[(size_t)row * N + col] = (bf16)v;
          if (EPI == 3) outF[(size_t)row * N + col] = v;
        }
      }
      s += __shfl_xor(s, 16); q += __shfl_xor(q, 16);
      s += __shfl_xor(s, 32); q += __shfl_xor(q, 32);
      if (quad == 0) {
        int col = n0 + wn + j * 16 + l15;
        atomicAdd(&gsum[col], s);
        atomicAdd(&gsq[col], q);
      }
    }
  }
}

// f32 -> bf16 bulk convert (8 elems/thread)
__global__ __launch_bounds__(256) void convf2b_k(const float* __restrict__ src,
    bf16* __restrict__ dst, size_t n8) {
  size_t i = (size_t)blockIdx.x * 256 + threadIdx.x;
  if (i < n8) {
    const float4* s = reinterpret_cast<const float4*>(src + i * 8);
    float4 a = s[0], b = s[1];
    bf16x8 o;
    o[0] = (bf16)a.x; o[1] = (bf16)a.y; o[2] = (bf16)a.z; o[3] = (bf16)a.w;
    o[4] = (bf16)b.x; o[5] = (bf16)b.y; o[6] = (bf16)b.z; o[7] = (bf16)b.w;
    reinterpret_cast<bf16x8*>(dst)[i] = o;
  }
}

// pooledB = bf16(pooledF * invc[row])
__global__ __launch_bounds__(256) void pconv_k(const float* __restrict__ pooledF,
    const float* __restrict__ invc, bf16* __restrict__ pooledB, int O) {
  size_t i = (size_t)blockIdx.x * 256 + threadIdx.x;
  if (i < (size_t)O * 64) {
    int o = (int)(i >> 6);
    float ic = invc[o];
    const float4* s = reinterpret_cast<const float4*>(pooledF + i * 8);
    float4 a = s[0], b = s[1];
    bf16x8 v;
    v[0] = (bf16)(a.x * ic); v[1] = (bf16)(a.y * ic);
    v[2] = (bf16)(a.z * ic); v[3] = (bf16)(a.w * ic);
    v[4] = (bf16)(b.x * ic); v[5] = (bf16)(b.y * ic);
    v[6] = (bf16)(b.z * ic); v[7] = (bf16)(b.w * ic);
    reinterpret_cast<bf16x8*>(pooledB)[i] = v;
  }
}

// Fused: A2 = bn_lrelu(hA) in-place + column sums + transposed chunk A2T[c][t-t0]
// (row stride TCp). One block per 64-row band, processed as TWO 32-row sub-tiles
// reusing one LDS buffer (keeps static LDS at ~41.5 KB). Rows >= T zero-padded.
__global__ __launch_bounds__(256) void trans_act_k(bf16* __restrict__ hA,
    const float* __restrict__ scale, const float* __restrict__ shift,
    float* __restrict__ csum, bf16* __restrict__ A2T,
    int t0, int TCp, int T) {
  __shared__ __align__(16) bf16 ld[32][520];
  __shared__ float cs_sh[4][512];
  const int tid = threadIdx.x;
  const int c8 = (tid & 63) * 8;
  const int rq = tid >> 6;           // 0..3
  const int bt0 = t0 + blockIdx.x * 64;
  const int tl = bt0 - t0;

  float sc[8], sf[8];
  #pragma unroll
  for (int j = 0; j < 8; ++j) { sc[j] = scale[c8 + j]; sf[j] = shift[c8 + j]; }
  float acc[8];
  #pragma unroll
  for (int j = 0; j < 8; ++j) acc[j] = 0.f;

  #pragma unroll
  for (int sub = 0; sub < 2; ++sub) {
    #pragma unroll
    for (int i = 0; i < 8; ++i) {
      int r = rq * 8 + i;                 // 0..31 within sub-tile
      int row = bt0 + sub * 32 + r;
      bf16x8 o;
      if (row < T) {
        bf16x8 v = *reinterpret_cast<const bf16x8*>(hA + (size_t)row * 512 + c8);
        #pragma unroll
        for (int j = 0; j < 8; ++j) {
          float f = sc[j] * (float)v[j] + sf[j];
          f = f >= 0.f ? f : 0.2f * f;
          o[j] = (bf16)f;
          acc[j] += (float)o[j];          // bf16-rounded value GEMM2 will see
        }
        *reinterpret_cast<bf16x8*>(hA + (size_t)row * 512 + c8) = o;
      } else {
        #pragma unroll
        for (int j = 0; j < 8; ++j) o[j] = (bf16)0.f;
      }
      *reinterpret_cast<bf16x8*>(&ld[r][c8]) = o;
    }
    __syncthreads();
    for (int cc = tid; cc < 512; cc += 256) {
      #pragma unroll
      for (int g8 = 0; g8 < 4; ++g8) {
        bf16x8 o;
        #pragma unroll
        for (int e = 0; e < 8; ++e) o[e] = ld[g8 * 8 + e][cc];
        *reinterpret_cast<bf16x8*>(A2T + (size_t)cc * TCp + tl + sub * 32 + g8 * 8) = o;
      }
    }
    __syncthreads();
  }
  #pragma unroll
  for (int j = 0; j < 8; ++j) cs_sh[rq][c8 + j] = acc[j];
  __syncthreads();
  for (int c = tid; c < 512; c += 256) {
    float s = cs_sh[0][c] + cs_sh[1][c] + cs_sh[2][c] + cs_sh[3][c];
    atomicAdd(&csum[c], s);
  }
}

// Gram over a transposed chunk: G += A2T_chunk @ A2T_chunk^T (contraction over t).
// Standard GEMM staging (GLL16 + swizzle); 10 upper-triangle 128x128 tile pairs x NS
// T-splits; off-diagonal mirrored at write.
__global__ __launch_bounds__(256) void gram2_k(const bf16* __restrict__ A2T,
    float* __restrict__ G, int TCp, int NS) {
  __shared__ __align__(16) bf16 As[128 * 64];
  __shared__ __align__(16) bf16 Bs[128 * 64];
  const int tid = threadIdx.x;
  const int pair = blockIdx.x % 10;
  const int s    = blockIdx.x / 10;
  const int K1T[10] = {0, 0, 0, 0, 1, 1, 1, 2, 2, 3};
  const int K2T[10] = {0, 1, 2, 3, 1, 2, 3, 2, 3, 3};
  const int k1b = K1T[pair], k2b = K2T[pair];
  const int lane = tid & 63;
  const int w = tid >> 6;
  const int wm = (w >> 1) * 64;
  const int wn = (w & 1) * 64;
  const int l15 = lane & 15;
  const int quad = lane >> 4;
  const int rsub = lane >> 3;
  const int cch  = lane & 7;

  const int NG = TCp >> 6;
  const int GPB = (NG + NS - 1) / NS;
  const int g0 = s * GPB;
  const int gend = min(NG, g0 + GPB);
  if (g0 >= gend) return;

  f32x4 acc[4][4];
  #pragma unroll
  for (int i = 0; i < 4; ++i)
    #pragma unroll
    for (int j = 0; j < 4; ++j)
      acc[i][j] = (f32x4){0.f, 0.f, 0.f, 0.f};

  const bool diag = (k1b == k2b);
  const bf16* BsP = diag ? As : Bs;

  for (int g = g0; g < gend; ++g) {
    const int t0 = g << 6;
    #pragma unroll
    for (int it = 0; it < 4; ++it) {
      int blk = it * 4 + w;
      int r = blk * 8 + rsub;
      int cs = cch ^ (r & 7);
      const bf16* src = A2T + (size_t)(k1b * 128 + r) * TCp + t0 + cs * 8;
      GLL16(src, &As[blk * 512]);
    }
    if (!diag) {
      #pragma unroll
      for (int it = 0; it < 4; ++it) {
        int blk = it * 4 + w;
        int r = blk * 8 + rsub;
        int cs = cch ^ (r & 7);
        const bf16* src = A2T + (size_t)(k2b * 128 + r) * TCp + t0 + cs * 8;
        GLL16(src, &Bs[blk * 512]);
      }
    }
    __syncthreads();
    #pragma unroll
    for (int kk = 0; kk < 64; kk += 32) {
      bf16x8 af[4], bfv[4];
      #pragma unroll
      for (int i = 0; i < 4; ++i) {
        int r = wm + i * 16 + l15;
        int ci = (kk >> 3) + quad;
        af[i] = *reinterpret_cast<const bf16x8*>(&As[r * 64 + ((ci ^ (r & 7)) << 3)]);
      }
      #pragma unroll
      for (int j = 0; j < 4; ++j) {
        int r = wn + j * 16 + l15;
        int ci = (kk >> 3) + quad;
        bfv[j] = *reinterpret_cast<const bf16x8*>(&BsP[r * 64 + ((ci ^ (r & 7)) << 3)]);
      }
      #pragma unroll
      for (int i = 0; i < 4; ++i)
        #pragma unroll
        for (int j = 0; j < 4; ++j)
          acc[i][j] = __builtin_amdgcn_mfma_f32_16x16x32_bf16(af[i], bfv[j], acc[i][j], 0, 0, 0);
    }
    __syncthreads();
  }

  #pragma unroll
  for (int i = 0; i < 4; ++i) {
    #pragma unroll
    for (int r = 0; r < 4; ++r) {
      int grow = k1b * 128 + wm + i * 16 + quad * 4 + r;
      #pragma unroll
      for (int j = 0; j < 4; ++j) {
        int gcol = k2b * 128 + wn + j * 16 + l15;
        float v = acc[i][j][r];
        atomicAdd(&G[(size_t)grow * 512 + gcol], v);
        if (!diag) atomicAdd(&G[(size_t)gcol * 512 + grow], v);
      }
    }
  }
}

// Chunked CSR pooling from dense chunk buffer ([s 512 | o 512] bf16 per row).
__global__ __launch_bounds__(256) void gatherc_k(const bf16* __restrict__ buf,
    const int* __restrict__ rowptr, const int* __restrict__ list,
    float* __restrict__ pooled, int c0, int c1, int O) {
  int o = blockIdx.x * 4 + (threadIdx.x >> 6);
  if (o >= O) return;
  int lane = threadIdx.x & 63;
  int cc = lane * 8;
  int e0 = rowptr[o], e1 = rowptr[o + 1];
  float acc[8];
  #pragma unroll
  for (int j = 0; j < 8; ++j) acc[j] = 0.f;
  bool any = false;
  for (int e = e0; e < e1; ++e) {
    int id = list[e];
    int t = id >> 1;
    if (t < c0 || t >= c1) continue;
    const bf16* row = buf + (size_t)(t - c0) * 1024 + (id & 1) * 512 + cc;
    bf16x8 v = *reinterpret_cast<const bf16x8*>(row);
    #pragma unroll
    for (int j = 0; j < 8; ++j) acc[j] += (float)v[j];
    any = true;
  }
  if (!any) return;
  float* dst = pooled + (size_t)o * 512 + cc;
  float4 a = *reinterpret_cast<float4*>(dst);
  float4 b = *reinterpret_cast<float4*>(dst + 4);
  a.x += acc[0]; a.y += acc[1]; a.z += acc[2]; a.w += acc[3];
  b.x += acc[4]; b.y += acc[5]; b.z += acc[6]; b.w += acc[7];
  *reinterpret_cast<float4*>(dst) = a;
  *reinterpret_cast<float4*>(dst + 4) = b;
}

// ---------- legacy fallback-tier kernels (small workspace) ----------
__global__ __launch_bounds__(256) void gram_k(const bf16* __restrict__ A2,
                                              float* __restrict__ G, int T) {
  __shared__ __align__(16) bf16 Ks[2][128][LDT];
  const int tid = threadIdx.x;
  const int tile = blockIdx.x % 10;
  const int s    = blockIdx.x / 10;
  const int NS   = gridDim.x / 10;
  const int K1T[10] = {0, 0, 0, 0, 1, 1, 1, 2, 2, 3};
  const int K2T[10] = {0, 1, 2, 3, 1, 2, 3, 2, 3, 3};
  const int k1b = K1T[tile], k2b = K2T[tile];
  const int lane = tid & 63;
  const int w = tid >> 6;
  const int wm = (w >> 1) * 64;
  const int wn = (w & 1) * 64;
  const int l15 = lane & 15;
  const int quad = lane >> 4;
  const int NG = (T + 63) >> 6;
  const int GPB = (NG + NS - 1) / NS;
  const int g0 = s * GPB;
  const int gend = min(NG, g0 + GPB);
  f32x4 acc[4][4];
  #pragma unroll
  for (int i = 0; i < 4; ++i)
    #pragma unroll
    for (int j = 0; j < 4; ++j)
      acc[i][j] = (f32x4){0.f, 0.f, 0.f, 0.f};
  const int bsel = (k1b == k2b) ? 0 : 1;
  for (int g = g0; g < gend; ++g) {
    const int t0 = g << 6;
    #pragma unroll
    for (int it = 0; it < 4; ++it) {
      int lin = it * 256 + tid;
      int t = lin >> 4, c8 = lin & 15;
      int row = t0 + t;
      bf16x8 v;
      #pragma unroll
      for (int e = 0; e < 8; ++e) v[e] = (bf16)0.f;
      if (row < T)
        v = *reinterpret_cast<const bf16x8*>(A2 + (size_t)row * 512 + k1b * 128 + c8 * 8);
      int ts = t ^ ((c8 & 7) << 3);
      #pragma unroll
      for (int e = 0; e < 8; ++e) Ks[0][c8 * 8 + e][ts] = v[e];
    }
    if (bsel) {
      #pragma unroll
      for (int it = 0; it < 4; ++it) {
        int lin = it * 256 + tid;
        int t = lin >> 4, c8 = lin & 15;
        int row = t0 + t;
        bf16x8 v;
        #pragma unroll
        for (int e = 0; e < 8; ++e) v[e] = (bf16)0.f;
        if (row < T)
          v = *reinterpret_cast<const bf16x8*>(A2 + (size_t)row * 512 + k2b * 128 + c8 * 8);
        int ts = t ^ ((c8 & 7) << 3);
        #pragma unroll
        for (int e = 0; e < 8; ++e) Ks[1][c8 * 8 + e][ts] = v[e];
      }
    }
    __syncthreads();
    #pragma unroll
    for (int kk = 0; kk < 64; kk += 32) {
      bf16x8 af[4], bfv[4];
      #pragma unroll
      for (int i = 0; i < 4; ++i) {
        int r = wm + i * 16 + l15;
        int toff = (kk + quad * 8) ^ (((r >> 3) & 7) << 3);
        af[i] = *reinterpret_cast<const bf16x8*>(&Ks[0][r][toff]);
      }
      #pragma unroll
      for (int j = 0; j < 4; ++j) {
        int r = wn + j * 16 + l15;
        int toff = (kk + quad * 8) ^ (((r >> 3) & 7) << 3);
        bfv[j] = *reinterpret_cast<const bf16x8*>(&Ks[bsel][r][toff]);
      }
      #pragma unroll
      for (int i = 0; i < 4; ++i)
        #pragma unroll
        for (int j = 0; j < 4; ++j)
          acc[i][j] = __builtin_amdgcn_mfma_f32_16x16x32_bf16(af[i], bfv[j], acc[i][j], 0, 0, 0);
    }
    __syncthreads();
  }
  #pragma unroll
  for (int i = 0; i < 4; ++i) {
    #pragma unroll
    for (int r = 0; r < 4; ++r) {
      int grow = k1b * 128 + wm + i * 16 + quad * 4 + r;
      #pragma unroll
      for (int j = 0; j < 4; ++j) {
        int gcol = k2b * 128 + wn + j * 16 + l15;
        float v = acc[i][j][r];
        atomicAdd(&G[(size_t)grow * 512 + gcol], v);
        if (k1b != k2b)
          atomicAdd(&G[(size_t)gcol * 512 + grow], v);
      }
    }
  }
}

__global__ __launch_bounds__(256) void act_colsum_k(bf16* __restrict__ hA,
    const float* __restrict__ scale, const float* __restrict__ shift,
    float* __restrict__ csum, int T) {
  __shared__ float sh[4 * 512];
  const int tid = threadIdx.x;
  const int c0 = (tid & 63) * 8;
  const int rofs = tid >> 6;
  float sc[8], sf[8];
  #pragma unroll
  for (int j = 0; j < 8; ++j) { sc[j] = scale[c0 + j]; sf[j] = shift[c0 + j]; }
  float acc[8];
  #pragma unroll
  for (int j = 0; j < 8; ++j) acc[j] = 0.f;
  for (int r = blockIdx.x * 4 + rofs; r < T; r += gridDim.x * 4) {
    bf16x8 v = *reinterpret_cast<const bf16x8*>(hA + (size_t)r * 512 + c0);
    bf16x8 o;
    #pragma unroll
    for (int j = 0; j < 8; ++j) {
      float f = sc[j] * (float)v[j] + sf[j];
      f = f >= 0.f ? f : 0.2f * f;
      o[j] = (bf16)f;
      acc[j] += (float)o[j];
    }
    *reinterpret_cast<bf16x8*>(hA + (size_t)r * 512 + c0) = o;
  }
  #pragma unroll
  for (int j = 0; j < 8; ++j) sh[rofs * 512 + c0 + j] = acc[j];
  __syncthreads();
  for (int c = tid; c < 512; c += 256) {
    float s = sh[c] + sh[512 + c] + sh[1024 + c] + sh[1536 + c];
    atomicAdd(&csum[c], s);
  }
}
// ---------- end legacy ----------

__global__ __launch_bounds__(256) void colstat_k(const float* __restrict__ G,
    const float* __restrict__ csum, const float* __restrict__ W1b,
    float* __restrict__ sumB, float* __restrict__ sqB) {
  __shared__ float wL[4][512];
  __shared__ float rq[4][4], rs[4][4];
  const int tid = threadIdx.x;
  const int c0 = blockIdx.x * 4;
  for (int idx = tid; idx < 2048; idx += 256) {
    int c = idx >> 9, k = idx & 511;
    wL[c][k] = W1b[(size_t)k * 1152 + c0 + c];
  }
  __syncthreads();
  float pq[4] = {0.f, 0.f, 0.f, 0.f};
  float ps[4] = {0.f, 0.f, 0.f, 0.f};
  for (int e = tid; e < 512 * 512; e += 256) {
    int i = e >> 9, j = e & 511;
    float g = G[e];
    #pragma unroll
    for (int c = 0; c < 4; ++c) pq[c] += g * wL[c][i] * wL[c][j];
  }
  for (int k = tid; k < 512; k += 256) {
    float cs = csum[k];
    #pragma unroll
    for (int c = 0; c < 4; ++c) ps[c] += cs * wL[c][k];
  }
  #pragma unroll
  for (int c = 0; c < 4; ++c) {
    #pragma unroll
    for (int off = 32; off > 0; off >>= 1) {
      pq[c] += __shfl_xor(pq[c], off);
      ps[c] += __shfl_xor(ps[c], off);
    }
  }
  const int w = tid >> 6, lane = tid & 63;
  if (lane == 0) {
    #pragma unroll
    for (int c = 0; c < 4; ++c) { rq[w][c] = pq[c]; rs[w][c] = ps[c]; }
  }
  __syncthreads();
  if (tid < 4) {
    sqB[c0 + tid]  = rq[0][tid] + rq[1][tid] + rq[2][tid] + rq[3][tid];
    sumB[c0 + tid] = rs[0][tid] + rs[1][tid] + rs[2][tid] + rs[3][tid];
  }
}

__global__ __launch_bounds__(256) void tconv_k(const float* __restrict__ W,
                                               bf16* __restrict__ WT, int K, int N) {
  int idx = blockIdx.x * 256 + threadIdx.x;
  if (idx < K * N) {
    int n = idx / K, k = idx - n * K;
    WT[(size_t)n * K + k] = (bf16)W[(size_t)k * N + n];
  }
}

__global__ __launch_bounds__(256) void bnfin_k(const float* __restrict__ sum,
    const float* __restrict__ sq, const float* __restrict__ g,
    const float* __restrict__ be, float* __restrict__ scale,
    float* __restrict__ shift, int C, float invR) {
  int c = blockIdx.x * 256 + threadIdx.x;
  if (c < C) {
    float m = sum[c] * invR;
    float v = sq[c] * invR - m * m;
    float a = g[c] * rsqrtf(v + 1e-5f);
    scale[c] = a;
    shift[c] = be[c] - m * a;
  }
}

__global__ __launch_bounds__(256) void cntint_k(const int* __restrict__ edges,
                                                int* __restrict__ cnt, int T) {
  int t = blockIdx.x * 256 + threadIdx.x;
  if (t < T) {
    atomicAdd(&cnt[edges[2 * t]], 1);
    atomicAdd(&cnt[edges[2 * t + 1]], 1);
  }
}

__global__ __launch_bounds__(256) void invcnt_k(const int* __restrict__ cnt,
                                                float* __restrict__ invc, int O) {
  int i = blockIdx.x * 256 + threadIdx.x;
  if (i < O) {
    float c = fminf(fmaxf((float)cnt[i], 1.f), (float)O);
    invc[i] = 1.f / c;
  }
}

__global__ __launch_bounds__(1024) void scan_k(const int* __restrict__ cnt,
    int* __restrict__ rowptr, int* __restrict__ head, int O, int total) {
  __shared__ int sh[1024];
  const int t = threadIdx.x;
  const int C = (O + 1023) / 1024;
  const int i0 = t * C;
  int s = 0;
  for (int i = 0; i < C; ++i) { int idx = i0 + i; if (idx < O) s += cnt[idx]; }
  sh[t] = s;
  __syncthreads();
  for (int d = 1; d < 1024; d <<= 1) {
    int v = (t >= d) ? sh[t - d] : 0;
    __syncthreads();
    sh[t] += v;
    __syncthreads();
  }
  int run = (t == 0) ? 0 : sh[t - 1];
  for (int i = 0; i < C; ++i) {
    int idx = i0 + i;
    if (idx < O) { rowptr[idx] = run; head[idx] = run; run += cnt[idx]; }
  }
  if (t == 0) rowptr[O] = total;
}

__global__ __launch_bounds__(256) void fill_k(const int* __restrict__ edges,
    int* __restrict__ head, int* __restrict__ list, int T) {
  int t = blockIdx.x * 256 + threadIdx.x;
  if (t < T) {
    int s = edges[2 * t];
    int p = atomicAdd(&head[s], 1);
    list[p] = t << 1;
    int o = edges[2 * t + 1];
    p = atomicAdd(&head[o], 1);
    list[p] = (t << 1) | 1;
  }
}

__global__ __launch_bounds__(256) void final_k(float* __restrict__ buf,
    const float* __restrict__ scale, const float* __restrict__ shift, int n) {
  int i = blockIdx.x * 256 + threadIdx.x;
  if (i < n) {
    int c = i & 127;
    float v = scale[c] * buf[i] + shift[c];
    buf[i] = v >= 0.f ? v : 0.2f * v;
  }
}

extern "C" void kernel_launch(void* const* d_in, const int* in_sizes, int n_in,
                              void* d_out, int out_size, void* d_ws, size_t ws_size,
                              hipStream_t stream) {
  const float* obj   = (const float*)d_in[0];
  const float* pred  = (const float*)d_in[1];
  const int*   edges = (const int*)d_in[2];
  const float* W1a = (const float*)d_in[3];
  const float* g1a = (const float*)d_in[5];
  const float* be1a= (const float*)d_in[6];
  const float* W1b = (const float*)d_in[7];
  const float* g1b = (const float*)d_in[9];
  const float* be1b= (const float*)d_in[10];
  const float* W2a = (const float*)d_in[11];
  const float* g2a = (const float*)d_in[13];
  const float* be2a= (const float*)d_in[14];
  const float* W2b = (const float*)d_in[15];
  const float* g2b = (const float*)d_in[17];
  const float* be2b= (const float*)d_in[18];

  const int O = in_sizes[0] / 128;
  const int T = in_sizes[1] / 128;
  float* out_obj = (float*)d_out;
  float* out_p   = (float*)d_out + (size_t)O * 128;

  char* base = (char*)d_ws;
  size_t off = 0;
  auto alloc = [&](size_t bytes) { size_t p = off; off += (bytes + 255) & ~(size_t)255; return p; };
  size_t oWT1a = alloc((size_t)384 * 512 * 2);
  size_t oWT1b = alloc((size_t)512 * 1152 * 2);
  size_t oWT2a = alloc((size_t)512 * 512 * 2);
  size_t oWT2b = alloc((size_t)512 * 128 * 2);
  size_t oSums = alloc(4608 * 4);
  size_t oScl  = alloc(4608 * 4);
  size_t oG    = alloc((size_t)512 * 512 * 4);
  size_t oCsum = alloc(512 * 4);
  size_t oCnt  = alloc((size_t)O * 4);
  size_t oInvc = alloc((size_t)O * 4);
  size_t oRp   = alloc((size_t)(O + 1) * 4);
  size_t oHead = alloc((size_t)O * 4);
  size_t oList = alloc((size_t)2 * T * 4);
  size_t oHA   = alloc((size_t)T * 512 * 2);    // hA/A2; later h2 + pooledB
  size_t oPool = off;                           // pooledF f32 (O,512); also A2T chunks
  size_t oBuf  = oPool + (((size_t)O * 512 * 4 + 255) & ~(size_t)255);

  // chunk buffer for GEMM2 output (rows of 1024 bf16)
  int chunkT = 0;
  if (ws_size > oBuf) {
    size_t ct = (ws_size - oBuf) / 2048;
    if (ct > (size_t)T) ct = T;
    chunkT = (int)(ct & ~(size_t)127);
  }
  const bool chunked = (chunkT >= 8192);

  // A2T chunking within pooledF region (leave one 64-group of pad room)
  long long crll = ((long long)O * 2 & ~63LL) - 64;
  int chunkR = (int)(crll < 64 ? 64 : crll);
  if (chunkR > T) chunkR = (T + 63) & ~63;

  // bf16 obj/pred copies in buf region (only alive before GEMM1)
  size_t objB_sz  = (((size_t)O * 128 * 2) + 255) & ~(size_t)255;
  size_t predB_sz = (size_t)T * 128 * 2;
  const bool canConv = chunked && (ws_size >= oBuf + objB_sz + predB_sz);

  bf16* WT1a = (bf16*)(base + oWT1a);
  bf16* WT1b = (bf16*)(base + oWT1b);
  bf16* WT2a = (bf16*)(base + oWT2a);
  bf16* WT2b = (bf16*)(base + oWT2b);
  float* sums = (float*)(base + oSums);
  float* sumA = sums,        * sqA = sums + 512;
  float* sumB = sums + 1024, * sqB = sums + 2176;
  float* sumC = sums + 3328, * sqC = sums + 3840;
  float* sumD = sums + 4352, * sqD = sums + 4480;
  float* scl = (float*)(base + oScl);
  float* scaleA = scl,        * shiftA = scl + 512;
  float* scaleB = scl + 1024, * shiftB = scl + 2176;
  float* scaleC = scl + 3328, * shiftC = scl + 3840;
  float* scaleD = scl + 4352, * shiftD = scl + 4480;
  float* Gm   = (float*)(base + oG);
  float* csum = (float*)(base + oCsum);
  int*   cntI = (int*)(base + oCnt);
  float* invc = (float*)(base + oInvc);
  int*   rowptr = (int*)(base + oRp);
  int*   head = (int*)(base + oHead);
  int*   list = (int*)(base + oList);
  bf16*  hA = (bf16*)(base + oHA);
  bf16*  h2 = (bf16*)(base + oHA);
  bf16*  pooledB = (bf16*)(base + oHA + (size_t)O * 512 * 4);  // after h2, hA dead
  float* pooledF = (float*)(base + oPool);
  bf16*  A2T = (bf16*)(base + oPool);
  bf16*  buf = (bf16*)(base + oBuf);
  bf16*  objB  = (bf16*)(base + oBuf);
  bf16*  predB = (bf16*)(base + oBuf + objB_sz);
  float* objpre = out_obj;

  hipMemsetAsync(sums, 0, 4608 * 4, stream);
  hipMemsetAsync(cntI, 0, (size_t)O * 4, stream);
  hipMemsetAsync(Gm, 0, (size_t)512 * 512 * 4, stream);
  hipMemsetAsync(csum, 0, 512 * 4, stream);
  if (!chunked) hipMemsetAsync(pooledF, 0, (size_t)O * 512 * 4, stream);

  tconv_k<<<(384 * 512 + 255) / 256, 256, 0, stream>>>(W1a, WT1a, 384, 512);
  tconv_k<<<(512 * 1152 + 255) / 256, 256, 0, stream>>>(W1b, WT1b, 512, 1152);
  tconv_k<<<(512 * 512 + 255) / 256, 256, 0, stream>>>(W2a, WT2a, 512, 512);
  tconv_k<<<(512 * 128 + 255) / 256, 256, 0, stream>>>(W2b, WT2b, 512, 128);
  cntint_k<<<(T + 255) / 256, 256, 0, stream>>>(edges, cntI, T);
  invcnt_k<<<(O + 255) / 256, 256, 0, stream>>>(cntI, invc, O);
  if (chunked) {
    scan_k<<<1, 1024, 0, stream>>>(cntI, rowptr, head, O, 2 * T);
    fill_k<<<(T + 255) / 256, 256, 0, stream>>>(edges, head, list, T);
  }
  if (canConv) {
    convf2b_k<<<(int)(((size_t)O * 16 + 255) / 256), 256, 0, stream>>>(obj, objB, (size_t)O * 16);
    convf2b_k<<<(int)(((size_t)T * 16 + 255) / 256), 256, 0, stream>>>(pred, predB, (size_t)T * 16);
  }

  const int Tb = (T + BM - 1) / BM;
  const int Ob = (O + BM - 1) / BM;

  // GEMM1: gathered (T,384) @ W1a -> hA raw bf16 + statsA
  {
    dim3 g(512 / BN, Tb);
    if (canConv)
      gemm_k<5, 0><<<g, 256, 0, stream>>>(nullptr, nullptr, (const float*)objB,
          (const float*)predB, edges, nullptr, nullptr, nullptr, nullptr, nullptr,
          WT1a, hA, nullptr, nullptr, sumA, sqA, T, 512, 384, 0);
    else
      gemm_k<0, 0><<<g, 256, 0, stream>>>(nullptr, nullptr, obj, pred, edges, nullptr,
          nullptr, nullptr, nullptr, nullptr, WT1a, hA, nullptr, nullptr, sumA, sqA,
          T, 512, 384, 0);
  }
  bnfin_k<<<2, 256, 0, stream>>>(sumA, sqA, g1a, be1a, scaleA, shiftA, 512, 1.f / T);

  if (chunked) {
    // act + colsum + transpose (A2T chunks in pooledF region), gram per chunk
    for (int t0 = 0; t0 < T; t0 += chunkR) {
      int TC = min(T - t0, chunkR);
      int TCp = (TC + 63) & ~63;
      trans_act_k<<<TCp / 64, 256, 0, stream>>>(hA, scaleA, shiftA, csum, A2T,
          t0, TCp, T);
      gram2_k<<<10 * 64, 256, 0, stream>>>(A2T, Gm, TCp, 64);
    }
    colstat_k<<<288, 256, 0, stream>>>(Gm, csum, W1b, sumB, sqB);
    bnfin_k<<<5, 256, 0, stream>>>(sumB, sqB, g1b, be1b, scaleB, shiftB, 1152, 1.f / T);

    // pooledF region now free of A2T -> zero it, then chunked GEMM2 + CSR pooling
    hipMemsetAsync(pooledF, 0, (size_t)O * 512 * 4, stream);
    for (int c0 = 0; c0 < T; c0 += chunkT) {
      int c1 = min(T, c0 + chunkT);
      dim3 g(1152 / BN, (c1 - c0 + BM - 1) / BM);
      gemm_k<3, 5><<<g, 256, 0, stream>>>(hA, nullptr, nullptr, nullptr, nullptr,
          nullptr, nullptr, nullptr, scaleB, shiftB, WT1b, buf, out_p, nullptr,
          nullptr, nullptr, c1, 1152, 512, c0);
      gatherc_k<<<(O + 3) / 4, 256, 0, stream>>>(buf, rowptr, list, pooledF, c0, c1, O);
    }
    // GEMM3 fast path: pooledB = bf16(pooledF * invc)
    pconv_k<<<(int)(((size_t)O * 64 + 255) / 256), 256, 0, stream>>>(pooledF, invc,
        pooledB, O);
    {
      dim3 g(512 / BN, Ob);
      gemm_k<3, 0><<<g, 256, 0, stream>>>(pooledB, nullptr, nullptr, nullptr, nullptr,
          nullptr, nullptr, nullptr, nullptr, nullptr, WT2a, h2, nullptr, nullptr,
          sumC, sqC, O, 512, 512, 0);
    }
  } else {
    // fallback tier: legacy act+gram, atomic-scatter GEMM2, f32 GEMM3
    act_colsum_k<<<1024, 256, 0, stream>>>(hA, scaleA, shiftA, csum, T);
    gram_k<<<10 * 48, 256, 0, stream>>>(hA, Gm, T);
    colstat_k<<<288, 256, 0, stream>>>(Gm, csum, W1b, sumB, sqB);
    bnfin_k<<<5, 256, 0, stream>>>(sumB, sqB, g1b, be1b, scaleB, shiftB, 1152, 1.f / T);
    dim3 g2(1152 / BN, Tb);
    gemm_k<3, 2><<<g2, 256, 0, stream>>>(hA, nullptr, nullptr, nullptr, edges, nullptr,
        nullptr, nullptr, scaleB, shiftB, WT1b, nullptr, out_p, pooledF, nullptr,
        nullptr, T, 1152, 512, 0);
    dim3 g3(512 / BN, Ob);
    gemm_k<2, 0><<<g3, 256, 0, stream>>>(nullptr, pooledF, nullptr, nullptr, nullptr,
        invc, nullptr, nullptr, nullptr, nullptr, WT2a, h2, nullptr, nullptr,
        sumC, sqC, O, 512, 512, 0);
  }
  bnfin_k<<<2, 256, 0, stream>>>(sumC, sqC, g2a, be2a, scaleC, shiftC, 512, 1.f / O);

  // GEMM4: bn_lrelu(h2) (O,512) @ W2b -> objpre f32 (in d_out) + statsD
  {
    dim3 g(128 / BN, Ob);
    gemm_k<1, 3><<<g, 256, 0, stream>>>(h2, nullptr, nullptr, nullptr, nullptr, nullptr,
        scaleC, shiftC, nullptr, nullptr, WT2b, nullptr, objpre, nullptr, sumD, sqD,
        O, 128, 512, 0);
  }
  bnfin_k<<<1, 256, 0, stream>>>(sumD, sqD, g2b, be2b, scaleD, shiftD, 128, 1.f / O);

  final_k<<<((size_t)O * 128 + 255) / 256, 256, 0, stream>>>(objpre, scaleD, shiftD,
      (int)((size_t)O * 128));
}

// Round 7
// 1796.557 us; speedup vs baseline: 1.2368x; 1.2368x over previous
//
#include <hip/hip_runtime.h>

typedef __bf16 bf16;
typedef __bf16 bf16x4 __attribute__((ext_vector_type(4)));
typedef __bf16 bf16x8 __attribute__((ext_vector_type(8)));
typedef float  f32x4  __attribute__((ext_vector_type(4)));

#define BM 128
#define BN 128
#define BKT 64
#define LDT 72   // gram LDS row stride (t-dim padded)

#ifndef __has_builtin
#define __has_builtin(x) 0
#endif

// 16B direct global->LDS: wave-uniform LDS base, per-lane global src (lane*16B dest).
#if __has_builtin(__builtin_amdgcn_global_load_lds)
#define GLL16(srcp, basep) \
  __builtin_amdgcn_global_load_lds( \
      (const __attribute__((address_space(1))) unsigned int*)(srcp), \
      (__attribute__((address_space(3))) unsigned int*)(basep), 16, 0, 0)
#else
#define GLL16(srcp, basep) \
  (((bf16x8*)(basep))[lane] = *(const bf16x8*)(srcp))
#endif

// AMODE: 0 = gather concat [obj[s] | pred | obj[o]] (f32 -> bf16, VGPR path)
//        1 = bn_lrelu(scale*x+shift) applied to bf16 source
//        2 = f32 source * invcnt[row]
//        3 = plain bf16 copy (global_load_lds path)
//        5 = gather concat from PRE-CONVERTED bf16 objB/predB (global_load_lds path;
//            objB passed via `obj`, predB via `pred`)
// EPI:   0 = store bf16 + column stats atomics
//        2 = bn_lrelu then atomic scatter (tier-3 fallback)
//        3 = store f32 + column stats atomics
//        5 = bn_lrelu; cols<512 -> buf[(row-rbase)*1024+n1] bf16,
//            512..639 -> outF (new_p f32), >=640 -> buf[..+n1-128] bf16
template<int AMODE, int EPI>
__global__ __launch_bounds__(256) void gemm_k(
    const bf16* __restrict__ Abf, const float* __restrict__ Af32,
    const float* __restrict__ obj, const float* __restrict__ pred,
    const int* __restrict__ edges, const float* __restrict__ invcnt,
    const float* __restrict__ scale, const float* __restrict__ shift,
    const float* __restrict__ oscale, const float* __restrict__ oshift,
    const bf16* __restrict__ WT,      // (N,K) bf16, pre-transposed
    bf16* __restrict__ outB, float* __restrict__ outF,
    float* __restrict__ pooled, float* __restrict__ gsum, float* __restrict__ gsq,
    int M, int N, int K, int rbase)
{
  __shared__ __align__(16) bf16 As[BM * 64];
  __shared__ __align__(16) bf16 Bs[BN * 64];
  __shared__ float sc_sh[(AMODE == 1) ? 512 : 1];
  __shared__ float sh_sh[(AMODE == 1) ? 512 : 1];
  __shared__ float osc[(EPI == 2 || EPI == 5) ? BN : 1];
  __shared__ float osh[(EPI == 2 || EPI == 5) ? BN : 1];
  __shared__ int eS[(AMODE == 0 || AMODE == 5 || EPI == 2) ? BM : 1];
  __shared__ int eO[(AMODE == 0 || AMODE == 5 || EPI == 2) ? BM : 1];

  const int tid = threadIdx.x;

  // ---- XCD-aligned swizzle (bijective; tail handled linearly)
  int bx = blockIdx.x, by = blockIdx.y;
  {
    const int NX = gridDim.x, NY = gridDim.y;
    int L = by * NX + bx;
    int bpg = NX * 8;
    int nFull = NY >> 3;
    int Lfull = nFull * bpg;
    if (L < Lfull) {
      int g = L / bpg, w2 = L - g * bpg;
      by = (g << 3) + (w2 & 7);
      bx = w2 >> 3;
    } else {
      int r2 = L - Lfull;
      int q = r2 / NX;
      by = (nFull << 3) + q;
      bx = r2 - q * NX;
    }
  }
  const int m0 = rbase + by * BM;
  const int n0 = bx * BN;

  const int lane = tid & 63;
  const int w = tid >> 6;
  const int wm = (w >> 1) * 64;
  const int wn = (w & 1) * 64;
  const int l15 = lane & 15;
  const int quad = lane >> 4;

  if (AMODE == 1) {
    for (int c = tid; c < K; c += 256) { sc_sh[c] = scale[c]; sh_sh[c] = shift[c]; }
  }
  if (EPI == 2 || EPI == 5) {
    if (tid < BN) { osc[tid] = oscale[n0 + tid]; osh[tid] = oshift[n0 + tid]; }
  }
  if (AMODE == 0 || AMODE == 5 || EPI == 2) {
    if (tid < BM) {
      int r = m0 + tid; if (r >= M) r = M - 1;
      eS[tid] = edges[2 * r];
      eO[tid] = edges[2 * r + 1];
    }
  }
  __syncthreads();

  f32x4 acc[4][4];
  #pragma unroll
  for (int i = 0; i < 4; ++i)
    #pragma unroll
    for (int j = 0; j < 4; ++j)
      acc[i][j] = (f32x4){0.f, 0.f, 0.f, 0.f};

  const int rsub = lane >> 3;   // 0..7: row within 8-row block
  const int cch  = lane & 7;    // 16B chunk within row

  for (int k0 = 0; k0 < K; k0 += BKT) {
    // ---- stage B^T tile: 128 rows x 64 k, direct-to-LDS, source-swizzled
    #pragma unroll
    for (int it = 0; it < 4; ++it) {
      int blk = it * 4 + w;
      int r = blk * 8 + rsub;
      int cs = cch ^ (r & 7);
      const bf16* src = WT + (size_t)(n0 + r) * K + k0 + cs * 8;
      GLL16(src, &Bs[blk * 512]);
    }
    // ---- stage A tile
    if (AMODE == 3) {
      #pragma unroll
      for (int it = 0; it < 4; ++it) {
        int blk = it * 4 + w;
        int r = blk * 8 + rsub;
        int row = m0 + r; if (row >= M) row = M - 1;
        int cs = cch ^ (r & 7);
        const bf16* src = Abf + (size_t)row * K + k0 + cs * 8;
        GLL16(src, &As[blk * 512]);
      }
    } else if (AMODE == 5) {
      const bf16* objB  = (const bf16*)obj;
      const bf16* predB = (const bf16*)pred;
      #pragma unroll
      for (int it = 0; it < 4; ++it) {
        int blk = it * 4 + w;
        int r = blk * 8 + rsub;
        int row = m0 + r; if (row >= M) row = M - 1;
        int cs = cch ^ (r & 7);
        int k = k0 + cs * 8;
        const bf16* src;
        if (k0 < 128)      src = objB  + (size_t)eS[r] * 128 + k;
        else if (k0 < 256) src = predB + (size_t)row * 128 + (k - 128);
        else               src = objB  + (size_t)eO[r] * 128 + (k - 256);
        GLL16(src, &As[blk * 512]);
      }
    } else if (AMODE == 1) {
      int idx = tid;
      #pragma unroll
      for (int it = 0; it < 4; ++it, idx += 256) {
        int r = idx >> 3, ch = idx & 7;
        int row = m0 + r; if (row >= M) row = M - 1;
        bf16x8 v = *reinterpret_cast<const bf16x8*>(Abf + (size_t)row * K + k0 + ch * 8);
        bf16x8 o;
        #pragma unroll
        for (int e = 0; e < 8; ++e) {
          int c = k0 + ch * 8 + e;
          float f = sc_sh[c] * (float)v[e] + sh_sh[c];
          f = f >= 0.f ? f : 0.2f * f;
          o[e] = (bf16)f;
        }
        *reinterpret_cast<bf16x8*>(&As[r * 64 + ((ch ^ (r & 7)) << 3)]) = o;
      }
    } else {
      int idx = tid;
      #pragma unroll
      for (int it = 0; it < 8; ++it, idx += 256) {
        int r = idx >> 4, c4 = (idx & 15) << 2;
        int row = m0 + r; if (row >= M) row = M - 1;
        const float* src;
        float mul = 1.f;
        if (AMODE == 0) {
          int k = k0 + c4;
          if (k < 128)      src = obj  + (size_t)eS[r] * 128 + k;
          else if (k < 256) src = pred + (size_t)row * 128 + (k - 128);
          else              src = obj  + (size_t)eO[r] * 128 + (k - 256);
        } else {
          src = Af32 + (size_t)row * K + k0 + c4;
          mul = invcnt[row];
        }
        float4 v = *reinterpret_cast<const float4*>(src);
        bf16x4 o;
        o[0] = (bf16)(v.x * mul); o[1] = (bf16)(v.y * mul);
        o[2] = (bf16)(v.z * mul); o[3] = (bf16)(v.w * mul);
        int ch = c4 >> 3;
        int half = (c4 >> 2) & 1;
        *reinterpret_cast<bf16x4*>(&As[r * 64 + ((ch ^ (r & 7)) << 3) + (half << 2)]) = o;
      }
    }
    __syncthreads();
    #pragma unroll
    for (int kk = 0; kk < BKT; kk += 32) {
      bf16x8 af[4], bfv[4];
      #pragma unroll
      for (int i = 0; i < 4; ++i) {
        int r = wm + i * 16 + l15;
        int ci = (kk >> 3) + quad;
        af[i] = *reinterpret_cast<const bf16x8*>(&As[r * 64 + ((ci ^ (r & 7)) << 3)]);
      }
      #pragma unroll
      for (int j = 0; j < 4; ++j) {
        int r = wn + j * 16 + l15;
        int ci = (kk >> 3) + quad;
        bfv[j] = *reinterpret_cast<const bf16x8*>(&Bs[r * 64 + ((ci ^ (r & 7)) << 3)]);
      }
      #pragma unroll
      for (int i = 0; i < 4; ++i)
        #pragma unroll
        for (int j = 0; j < 4; ++j)
          acc[i][j] = __builtin_amdgcn_mfma_f32_16x16x32_bf16(af[i], bfv[j], acc[i][j], 0, 0, 0);
    }
    __syncthreads();
  }

  if (EPI == 2) {
    #pragma unroll
    for (int i = 0; i < 4; ++i) {
      #pragma unroll
      for (int r = 0; r < 4; ++r) {
        int lrow = wm + i * 16 + quad * 4 + r;
        int row = m0 + lrow;
        if (row >= M) continue;
        #pragma unroll
        for (int j = 0; j < 4; ++j) {
          int cl = wn + j * 16 + l15;
          int n1 = n0 + cl;
          float v = osc[cl] * acc[i][j][r] + osh[cl];
          v = v >= 0.f ? v : 0.2f * v;
          if (n1 < 512)      atomicAdd(&pooled[(size_t)eS[lrow] * 512 + n1], v);
          else if (n1 < 640) outF[(size_t)row * 128 + (n1 - 512)] = v;
          else               atomicAdd(&pooled[(size_t)eO[lrow] * 512 + (n1 - 640)], v);
        }
      }
    }
  } else if (EPI == 5) {
    #pragma unroll
    for (int i = 0; i < 4; ++i) {
      #pragma unroll
      for (int r = 0; r < 4; ++r) {
        int lrow = wm + i * 16 + quad * 4 + r;
        int row = m0 + lrow;
        if (row >= M) continue;
        #pragma unroll
        for (int j = 0; j < 4; ++j) {
          int cl = wn + j * 16 + l15;
          int n1 = n0 + cl;
          float v = osc[cl] * acc[i][j][r] + osh[cl];
          v = v >= 0.f ? v : 0.2f * v;
          if (n1 < 512)      outB[(size_t)(row - rbase) * 1024 + n1] = (bf16)v;
          else if (n1 < 640) outF[(size_t)row * 128 + (n1 - 512)] = v;
          else               outB[(size_t)(row - rbase) * 1024 + (n1 - 128)] = (bf16)v;
        }
      }
    }
  } else {
    #pragma unroll
    for (int j = 0; j < 4; ++j) {
      float s = 0.f, q = 0.f;
      #pragma unroll
      for (int i = 0; i < 4; ++i) {
        #pragma unroll
        for (int r = 0; r < 4; ++r) {
          int row = m0 + wm + i * 16 + quad * 4 + r;
          if (row >= M) continue;
          float v = acc[i][j][r];
          s += v; q += v * v;
          int col = n0 + wn + j * 16 + l15;
          if (EPI == 0) outB[(size_t)row * N + col] = (bf16)v;
          if (EPI == 3) outF[(size_t)row * N + col] = v;
        }
      }
      s += __shfl_xor(s, 16); q += __shfl_xor(q, 16);
      s += __shfl_xor(s, 32); q += __shfl_xor(q, 32);
      if (quad == 0) {
        int col = n0 + wn + j * 16 + l15;
        atomicAdd(&gsum[col], s);
        atomicAdd(&gsq[col], q);
      }
    }
  }
}

// f32 -> bf16 bulk convert (8 elems/thread)
__global__ __launch_bounds__(256) void convf2b_k(const float* __restrict__ src,
    bf16* __restrict__ dst, size_t n8) {
  size_t i = (size_t)blockIdx.x * 256 + threadIdx.x;
  if (i < n8) {
    const float4* s = reinterpret_cast<const float4*>(src + i * 8);
    float4 a = s[0], b = s[1];
    bf16x8 o;
    o[0] = (bf16)a.x; o[1] = (bf16)a.y; o[2] = (bf16)a.z; o[3] = (bf16)a.w;
    o[4] = (bf16)b.x; o[5] = (bf16)b.y; o[6] = (bf16)b.z; o[7] = (bf16)b.w;
    reinterpret_cast<bf16x8*>(dst)[i] = o;
  }
}

// pooledB = bf16(pooledF * invc[row])
__global__ __launch_bounds__(256) void pconv_k(const float* __restrict__ pooledF,
    const float* __restrict__ invc, bf16* __restrict__ pooledB, int O) {
  size_t i = (size_t)blockIdx.x * 256 + threadIdx.x;
  if (i < (size_t)O * 64) {
    int o = (int)(i >> 6);
    float ic = invc[o];
    const float4* s = reinterpret_cast<const float4*>(pooledF + i * 8);
    float4 a = s[0], b = s[1];
    bf16x8 v;
    v[0] = (bf16)(a.x * ic); v[1] = (bf16)(a.y * ic);
    v[2] = (bf16)(a.z * ic); v[3] = (bf16)(a.w * ic);
    v[4] = (bf16)(b.x * ic); v[5] = (bf16)(b.y * ic);
    v[6] = (bf16)(b.z * ic); v[7] = (bf16)(b.w * ic);
    reinterpret_cast<bf16x8*>(pooledB)[i] = v;
  }
}

// Gram matrix G = A2^T A2 (512x512 f32) over T rows. Upper-triangle tile pairs only
// (10 of 16); off-diagonal tiles mirror their result at write time. Split-K over T.
__global__ __launch_bounds__(256) void gram_k(const bf16* __restrict__ A2,
                                              float* __restrict__ G, int T) {
  __shared__ __align__(16) bf16 Ks[2][128][LDT];
  const int tid = threadIdx.x;
  const int tile = blockIdx.x % 10;
  const int s    = blockIdx.x / 10;
  const int NS   = gridDim.x / 10;
  const int K1T[10] = {0, 0, 0, 0, 1, 1, 1, 2, 2, 3};
  const int K2T[10] = {0, 1, 2, 3, 1, 2, 3, 2, 3, 3};
  const int k1b = K1T[tile], k2b = K2T[tile];
  const int lane = tid & 63;
  const int w = tid >> 6;
  const int wm = (w >> 1) * 64;
  const int wn = (w & 1) * 64;
  const int l15 = lane & 15;
  const int quad = lane >> 4;
  const int NG = (T + 63) >> 6;
  const int GPB = (NG + NS - 1) / NS;
  const int g0 = s * GPB;
  const int gend = min(NG, g0 + GPB);
  f32x4 acc[4][4];
  #pragma unroll
  for (int i = 0; i < 4; ++i)
    #pragma unroll
    for (int j = 0; j < 4; ++j)
      acc[i][j] = (f32x4){0.f, 0.f, 0.f, 0.f};
  const int bsel = (k1b == k2b) ? 0 : 1;
  for (int g = g0; g < gend; ++g) {
    const int t0 = g << 6;
    #pragma unroll
    for (int it = 0; it < 4; ++it) {
      int lin = it * 256 + tid;
      int t = lin >> 4, c8 = lin & 15;
      int row = t0 + t;
      bf16x8 v;
      #pragma unroll
      for (int e = 0; e < 8; ++e) v[e] = (bf16)0.f;
      if (row < T)
        v = *reinterpret_cast<const bf16x8*>(A2 + (size_t)row * 512 + k1b * 128 + c8 * 8);
      int ts = t ^ ((c8 & 7) << 3);
      #pragma unroll
      for (int e = 0; e < 8; ++e) Ks[0][c8 * 8 + e][ts] = v[e];
    }
    if (bsel) {
      #pragma unroll
      for (int it = 0; it < 4; ++it) {
        int lin = it * 256 + tid;
        int t = lin >> 4, c8 = lin & 15;
        int row = t0 + t;
        bf16x8 v;
        #pragma unroll
        for (int e = 0; e < 8; ++e) v[e] = (bf16)0.f;
        if (row < T)
          v = *reinterpret_cast<const bf16x8*>(A2 + (size_t)row * 512 + k2b * 128 + c8 * 8);
        int ts = t ^ ((c8 & 7) << 3);
        #pragma unroll
        for (int e = 0; e < 8; ++e) Ks[1][c8 * 8 + e][ts] = v[e];
      }
    }
    __syncthreads();
    #pragma unroll
    for (int kk = 0; kk < 64; kk += 32) {
      bf16x8 af[4], bfv[4];
      #pragma unroll
      for (int i = 0; i < 4; ++i) {
        int r = wm + i * 16 + l15;
        int toff = (kk + quad * 8) ^ (((r >> 3) & 7) << 3);
        af[i] = *reinterpret_cast<const bf16x8*>(&Ks[0][r][toff]);
      }
      #pragma unroll
      for (int j = 0; j < 4; ++j) {
        int r = wn + j * 16 + l15;
        int toff = (kk + quad * 8) ^ (((r >> 3) & 7) << 3);
        bfv[j] = *reinterpret_cast<const bf16x8*>(&Ks[bsel][r][toff]);
      }
      #pragma unroll
      for (int i = 0; i < 4; ++i)
        #pragma unroll
        for (int j = 0; j < 4; ++j)
          acc[i][j] = __builtin_amdgcn_mfma_f32_16x16x32_bf16(af[i], bfv[j], acc[i][j], 0, 0, 0);
    }
    __syncthreads();
  }
  #pragma unroll
  for (int i = 0; i < 4; ++i) {
    #pragma unroll
    for (int r = 0; r < 4; ++r) {
      int grow = k1b * 128 + wm + i * 16 + quad * 4 + r;
      #pragma unroll
      for (int j = 0; j < 4; ++j) {
        int gcol = k2b * 128 + wn + j * 16 + l15;
        float v = acc[i][j][r];
        atomicAdd(&G[(size_t)grow * 512 + gcol], v);
        if (k1b != k2b)
          atomicAdd(&G[(size_t)gcol * 512 + grow], v);
      }
    }
  }
}

// A2 = bn_lrelu(hA) in-place, fused with column sums of A2 (csum, f32[512]).
__global__ __launch_bounds__(256) void act_colsum_k(bf16* __restrict__ hA,
    const float* __restrict__ scale, const float* __restrict__ shift,
    float* __restrict__ csum, int T) {
  __shared__ float sh[4 * 512];
  const int tid = threadIdx.x;
  const int c0 = (tid & 63) * 8;
  const int rofs = tid >> 6;
  float sc[8], sf[8];
  #pragma unroll
  for (int j = 0; j < 8; ++j) { sc[j] = scale[c0 + j]; sf[j] = shift[c0 + j]; }
  float acc[8];
  #pragma unroll
  for (int j = 0; j < 8; ++j) acc[j] = 0.f;
  for (int r = blockIdx.x * 4 + rofs; r < T; r += gridDim.x * 4) {
    bf16x8 v = *reinterpret_cast<const bf16x8*>(hA + (size_t)r * 512 + c0);
    bf16x8 o;
    #pragma unroll
    for (int j = 0; j < 8; ++j) {
      float f = sc[j] * (float)v[j] + sf[j];
      f = f >= 0.f ? f : 0.2f * f;
      o[j] = (bf16)f;
      acc[j] += (float)o[j];   // accumulate the bf16-rounded value GEMM2 will see
    }
    *reinterpret_cast<bf16x8*>(hA + (size_t)r * 512 + c0) = o;
  }
  #pragma unroll
  for (int j = 0; j < 8; ++j) sh[rofs * 512 + c0 + j] = acc[j];
  __syncthreads();
  for (int c = tid; c < 512; c += 256) {
    float s = sh[c] + sh[512 + c] + sh[1024 + c] + sh[1536 + c];
    atomicAdd(&csum[c], s);
  }
}

// sqB[c] += w_c^T G[rs:rs+64,:] w_c for 4 columns per block; 8 row-slices per
// column group (grid = 288*8). float4 G loads + unroll -> many loads in flight.
__global__ __launch_bounds__(256) void colstat_k(const float* __restrict__ G,
    const float* __restrict__ W1b, float* __restrict__ sqB) {
  __shared__ float wL[4][512];
  __shared__ float rq[4][4];
  const int tid = threadIdx.x;
  const int c0 = (blockIdx.x >> 3) * 4;
  const int rs = (blockIdx.x & 7) * 64;
  for (int idx = tid; idx < 2048; idx += 256) {
    int c = idx >> 9, k = idx & 511;
    wL[c][k] = W1b[(size_t)k * 1152 + c0 + c];
  }
  __syncthreads();
  float pq[4] = {0.f, 0.f, 0.f, 0.f};
  // 64 rows x 512 cols = 8192 float4; 32 per thread
  #pragma unroll 4
  for (int v = tid; v < 8192; v += 256) {
    int i = rs + (v >> 7);
    int j = (v & 127) << 2;
    float4 g = *reinterpret_cast<const float4*>(G + (size_t)i * 512 + j);
    #pragma unroll
    for (int c = 0; c < 4; ++c) {
      float d = g.x * wL[c][j] + g.y * wL[c][j + 1]
              + g.z * wL[c][j + 2] + g.w * wL[c][j + 3];
      pq[c] += wL[c][i] * d;
    }
  }
  #pragma unroll
  for (int c = 0; c < 4; ++c) {
    #pragma unroll
    for (int off = 32; off > 0; off >>= 1) pq[c] += __shfl_xor(pq[c], off);
  }
  const int w = tid >> 6, lane = tid & 63;
  if (lane == 0) {
    #pragma unroll
    for (int c = 0; c < 4; ++c) rq[w][c] = pq[c];
  }
  __syncthreads();
  if (tid < 4)
    atomicAdd(&sqB[c0 + tid], rq[0][tid] + rq[1][tid] + rq[2][tid] + rq[3][tid]);
}

// sumB[c] += csum . W1b[k0:k0+128, c]  (grid = ceil(1152/256) * 4 k-slices)
__global__ __launch_bounds__(256) void sumb_k(const float* __restrict__ csum,
    const float* __restrict__ W1b, float* __restrict__ sumB) {
  int c = (blockIdx.x >> 2) * 256 + threadIdx.x;
  int k0 = (blockIdx.x & 3) * 128;
  if (c < 1152) {
    float s = 0.f;
    #pragma unroll 4
    for (int k = k0; k < k0 + 128; ++k) s += csum[k] * W1b[(size_t)k * 1152 + c];
    atomicAdd(&sumB[c], s);
  }
}

// Chunked CSR pooling from dense chunk buffer ([s 512 | o 512] bf16 per row).
__global__ __launch_bounds__(256) void gatherc_k(const bf16* __restrict__ buf,
    const int* __restrict__ rowptr, const int* __restrict__ list,
    float* __restrict__ pooled, int c0, int c1, int O) {
  int o = blockIdx.x * 4 + (threadIdx.x >> 6);
  if (o >= O) return;
  int lane = threadIdx.x & 63;
  int cc = lane * 8;
  int e0 = rowptr[o], e1 = rowptr[o + 1];
  float acc[8];
  #pragma unroll
  for (int j = 0; j < 8; ++j) acc[j] = 0.f;
  bool any = false;
  for (int e = e0; e < e1; ++e) {
    int id = list[e];
    int t = id >> 1;
    if (t < c0 || t >= c1) continue;
    const bf16* row = buf + (size_t)(t - c0) * 1024 + (id & 1) * 512 + cc;
    bf16x8 v = *reinterpret_cast<const bf16x8*>(row);
    #pragma unroll
    for (int j = 0; j < 8; ++j) acc[j] += (float)v[j];
    any = true;
  }
  if (!any) return;
  float* dst = pooled + (size_t)o * 512 + cc;
  float4 a = *reinterpret_cast<float4*>(dst);
  float4 b = *reinterpret_cast<float4*>(dst + 4);
  a.x += acc[0]; a.y += acc[1]; a.z += acc[2]; a.w += acc[3];
  b.x += acc[4]; b.y += acc[5]; b.z += acc[6]; b.w += acc[7];
  *reinterpret_cast<float4*>(dst) = a;
  *reinterpret_cast<float4*>(dst + 4) = b;
}

// transpose + fp32->bf16 convert: W (K,N) -> WT (N,K)
__global__ __launch_bounds__(256) void tconv_k(const float* __restrict__ W,
                                               bf16* __restrict__ WT, int K, int N) {
  int idx = blockIdx.x * 256 + threadIdx.x;
  if (idx < K * N) {
    int n = idx / K, k = idx - n * K;
    WT[(size_t)n * K + k] = (bf16)W[(size_t)k * N + n];
  }
}

__global__ __launch_bounds__(256) void bnfin_k(const float* __restrict__ sum,
    const float* __restrict__ sq, const float* __restrict__ g,
    const float* __restrict__ be, float* __restrict__ scale,
    float* __restrict__ shift, int C, float invR) {
  int c = blockIdx.x * 256 + threadIdx.x;
  if (c < C) {
    float m = sum[c] * invR;
    float v = sq[c] * invR - m * m;
    float a = g[c] * rsqrtf(v + 1e-5f);
    scale[c] = a;
    shift[c] = be[c] - m * a;
  }
}

__global__ __launch_bounds__(256) void cntint_k(const int* __restrict__ edges,
                                                int* __restrict__ cnt, int T) {
  int t = blockIdx.x * 256 + threadIdx.x;
  if (t < T) {
    atomicAdd(&cnt[edges[2 * t]], 1);
    atomicAdd(&cnt[edges[2 * t + 1]], 1);
  }
}

__global__ __launch_bounds__(256) void invcnt_k(const int* __restrict__ cnt,
                                                float* __restrict__ invc, int O) {
  int i = blockIdx.x * 256 + threadIdx.x;
  if (i < O) {
    float c = fminf(fmaxf((float)cnt[i], 1.f), (float)O);
    invc[i] = 1.f / c;
  }
}

__global__ __launch_bounds__(1024) void scan_k(const int* __restrict__ cnt,
    int* __restrict__ rowptr, int* __restrict__ head, int O, int total) {
  __shared__ int sh[1024];
  const int t = threadIdx.x;
  const int C = (O + 1023) / 1024;
  const int i0 = t * C;
  int s = 0;
  for (int i = 0; i < C; ++i) { int idx = i0 + i; if (idx < O) s += cnt[idx]; }
  sh[t] = s;
  __syncthreads();
  for (int d = 1; d < 1024; d <<= 1) {
    int v = (t >= d) ? sh[t - d] : 0;
    __syncthreads();
    sh[t] += v;
    __syncthreads();
  }
  int run = (t == 0) ? 0 : sh[t - 1];
  for (int i = 0; i < C; ++i) {
    int idx = i0 + i;
    if (idx < O) { rowptr[idx] = run; head[idx] = run; run += cnt[idx]; }
  }
  if (t == 0) rowptr[O] = total;
}

__global__ __launch_bounds__(256) void fill_k(const int* __restrict__ edges,
    int* __restrict__ head, int* __restrict__ list, int T) {
  int t = blockIdx.x * 256 + threadIdx.x;
  if (t < T) {
    int s = edges[2 * t];
    int p = atomicAdd(&head[s], 1);
    list[p] = t << 1;
    int o = edges[2 * t + 1];
    p = atomicAdd(&head[o], 1);
    list[p] = (t << 1) | 1;
  }
}

__global__ __launch_bounds__(256) void final_k(float* __restrict__ buf,
    const float* __restrict__ scale, const float* __restrict__ shift, int n) {
  int i = blockIdx.x * 256 + threadIdx.x;
  if (i < n) {
    int c = i & 127;
    float v = scale[c] * buf[i] + shift[c];
    buf[i] = v >= 0.f ? v : 0.2f * v;
  }
}

extern "C" void kernel_launch(void* const* d_in, const int* in_sizes, int n_in,
                              void* d_out, int out_size, void* d_ws, size_t ws_size,
                              hipStream_t stream) {
  const float* obj   = (const float*)d_in[0];
  const float* pred  = (const float*)d_in[1];
  const int*   edges = (const int*)d_in[2];
  const float* W1a = (const float*)d_in[3];
  const float* g1a = (const float*)d_in[5];
  const float* be1a= (const float*)d_in[6];
  const float* W1b = (const float*)d_in[7];
  const float* g1b = (const float*)d_in[9];
  const float* be1b= (const float*)d_in[10];
  const float* W2a = (const float*)d_in[11];
  const float* g2a = (const float*)d_in[13];
  const float* be2a= (const float*)d_in[14];
  const float* W2b = (const float*)d_in[15];
  const float* g2b = (const float*)d_in[17];
  const float* be2b= (const float*)d_in[18];

  const int O = in_sizes[0] / 128;
  const int T = in_sizes[1] / 128;
  float* out_obj = (float*)d_out;
  float* out_p   = (float*)d_out + (size_t)O * 128;

  char* base = (char*)d_ws;
  size_t off = 0;
  auto alloc = [&](size_t bytes) { size_t p = off; off += (bytes + 255) & ~(size_t)255; return p; };
  size_t oWT1a = alloc((size_t)384 * 512 * 2);
  size_t oWT1b = alloc((size_t)512 * 1152 * 2);
  size_t oWT2a = alloc((size_t)512 * 512 * 2);
  size_t oWT2b = alloc((size_t)512 * 128 * 2);
  size_t oSums = alloc(4608 * 4);
  size_t oScl  = alloc(4608 * 4);
  size_t oG    = alloc((size_t)512 * 512 * 4);
  size_t oCsum = alloc(512 * 4);
  size_t oCnt  = alloc((size_t)O * 4);
  size_t oInvc = alloc((size_t)O * 4);
  size_t oRp   = alloc((size_t)(O + 1) * 4);
  size_t oHead = alloc((size_t)O * 4);
  size_t oList = alloc((size_t)2 * T * 4);
  size_t oHA   = alloc((size_t)T * 512 * 2);    // hA/A2; later h2 + pooledB
  size_t oPool = off;                           // pooledF f32 (O,512)
  size_t oBuf  = oPool + (((size_t)O * 512 * 4 + 255) & ~(size_t)255);

  // chunk buffer for GEMM2 output (rows of 1024 bf16)
  int chunkT = 0;
  if (ws_size > oBuf) {
    size_t ct = (ws_size - oBuf) / 2048;
    if (ct > (size_t)T) ct = T;
    chunkT = (int)(ct & ~(size_t)127);
  }
  const bool chunked = (chunkT >= 8192);

  // bf16 obj/pred copies in buf region (only alive before GEMM1)
  size_t objB_sz  = (((size_t)O * 128 * 2) + 255) & ~(size_t)255;
  size_t predB_sz = (size_t)T * 128 * 2;
  const bool canConv = chunked && (ws_size >= oBuf + objB_sz + predB_sz);

  bf16* WT1a = (bf16*)(base + oWT1a);
  bf16* WT1b = (bf16*)(base + oWT1b);
  bf16* WT2a = (bf16*)(base + oWT2a);
  bf16* WT2b = (bf16*)(base + oWT2b);
  float* sums = (float*)(base + oSums);
  float* sumA = sums,        * sqA = sums + 512;
  float* sumB = sums + 1024, * sqB = sums + 2176;
  float* sumC = sums + 3328, * sqC = sums + 3840;
  float* sumD = sums + 4352, * sqD = sums + 4480;
  float* scl = (float*)(base + oScl);
  float* scaleA = scl,        * shiftA = scl + 512;
  float* scaleB = scl + 1024, * shiftB = scl + 2176;
  float* scaleC = scl + 3328, * shiftC = scl + 3840;
  float* scaleD = scl + 4352, * shiftD = scl + 4480;
  float* Gm   = (float*)(base + oG);
  float* csum = (float*)(base + oCsum);
  int*   cntI = (int*)(base + oCnt);
  float* invc = (float*)(base + oInvc);
  int*   rowptr = (int*)(base + oRp);
  int*   head = (int*)(base + oHead);
  int*   list = (int*)(base + oList);
  bf16*  hA = (bf16*)(base + oHA);
  bf16*  h2 = (bf16*)(base + oHA);
  bf16*  pooledB = (bf16*)(base + oHA + (size_t)O * 512 * 4);  // after h2, hA dead
  float* pooledF = (float*)(base + oPool);
  bf16*  buf = (bf16*)(base + oBuf);
  bf16*  objB  = (bf16*)(base + oBuf);
  bf16*  predB = (bf16*)(base + oBuf + objB_sz);
  float* objpre = out_obj;

  hipMemsetAsync(sums, 0, 4608 * 4, stream);
  hipMemsetAsync(cntI, 0, (size_t)O * 4, stream);
  hipMemsetAsync(Gm, 0, (size_t)512 * 512 * 4, stream);
  hipMemsetAsync(csum, 0, 512 * 4, stream);
  hipMemsetAsync(pooledF, 0, (size_t)O * 512 * 4, stream);

  tconv_k<<<(384 * 512 + 255) / 256, 256, 0, stream>>>(W1a, WT1a, 384, 512);
  tconv_k<<<(512 * 1152 + 255) / 256, 256, 0, stream>>>(W1b, WT1b, 512, 1152);
  tconv_k<<<(512 * 512 + 255) / 256, 256, 0, stream>>>(W2a, WT2a, 512, 512);
  tconv_k<<<(512 * 128 + 255) / 256, 256, 0, stream>>>(W2b, WT2b, 512, 128);
  cntint_k<<<(T + 255) / 256, 256, 0, stream>>>(edges, cntI, T);
  invcnt_k<<<(O + 255) / 256, 256, 0, stream>>>(cntI, invc, O);
  if (chunked) {
    scan_k<<<1, 1024, 0, stream>>>(cntI, rowptr, head, O, 2 * T);
    fill_k<<<(T + 255) / 256, 256, 0, stream>>>(edges, head, list, T);
  }
  if (canConv) {
    convf2b_k<<<(int)(((size_t)O * 16 + 255) / 256), 256, 0, stream>>>(obj, objB, (size_t)O * 16);
    convf2b_k<<<(int)(((size_t)T * 16 + 255) / 256), 256, 0, stream>>>(pred, predB, (size_t)T * 16);
  }

  const int Tb = (T + BM - 1) / BM;
  const int Ob = (O + BM - 1) / BM;

  // GEMM1: gathered (T,384) @ W1a -> hA raw bf16 + statsA
  {
    dim3 g(512 / BN, Tb);
    if (canConv)
      gemm_k<5, 0><<<g, 256, 0, stream>>>(nullptr, nullptr, (const float*)objB,
          (const float*)predB, edges, nullptr, nullptr, nullptr, nullptr, nullptr,
          WT1a, hA, nullptr, nullptr, sumA, sqA, T, 512, 384, 0);
    else
      gemm_k<0, 0><<<g, 256, 0, stream>>>(nullptr, nullptr, obj, pred, edges, nullptr,
          nullptr, nullptr, nullptr, nullptr, WT1a, hA, nullptr, nullptr, sumA, sqA,
          T, 512, 384, 0);
  }
  bnfin_k<<<2, 256, 0, stream>>>(sumA, sqA, g1a, be1a, scaleA, shiftA, 512, 1.f / T);

  // A2 = bn_lrelu(hA) in-place + column sums; G = A2^T A2; stats algebraically
  act_colsum_k<<<1024, 256, 0, stream>>>(hA, scaleA, shiftA, csum, T);
  gram_k<<<10 * 48, 256, 0, stream>>>(hA, Gm, T);
  colstat_k<<<288 * 8, 256, 0, stream>>>(Gm, W1b, sqB);
  sumb_k<<<((1152 + 255) / 256) * 4, 256, 0, stream>>>(csum, W1b, sumB);
  bnfin_k<<<5, 256, 0, stream>>>(sumB, sqB, g1b, be1b, scaleB, shiftB, 1152, 1.f / T);

  if (chunked) {
    // natural-order chunked GEMM2 with fused bn_lrelu; dense buf; CSR pooling
    for (int c0 = 0; c0 < T; c0 += chunkT) {
      int c1 = min(T, c0 + chunkT);
      dim3 g(1152 / BN, (c1 - c0 + BM - 1) / BM);
      gemm_k<3, 5><<<g, 256, 0, stream>>>(hA, nullptr, nullptr, nullptr, nullptr,
          nullptr, nullptr, nullptr, scaleB, shiftB, WT1b, buf, out_p, nullptr,
          nullptr, nullptr, c1, 1152, 512, c0);
      gatherc_k<<<(O + 3) / 4, 256, 0, stream>>>(buf, rowptr, list, pooledF, c0, c1, O);
    }
    // GEMM3 fast path: pooledB = bf16(pooledF * invc)
    pconv_k<<<(int)(((size_t)O * 64 + 255) / 256), 256, 0, stream>>>(pooledF, invc,
        pooledB, O);
    {
      dim3 g(512 / BN, Ob);
      gemm_k<3, 0><<<g, 256, 0, stream>>>(pooledB, nullptr, nullptr, nullptr, nullptr,
          nullptr, nullptr, nullptr, nullptr, nullptr, WT2a, h2, nullptr, nullptr,
          sumC, sqC, O, 512, 512, 0);
    }
  } else {
    // tier-3: single GEMM2 pass with atomic scatter; f32 GEMM3
    dim3 g2(1152 / BN, Tb);
    gemm_k<3, 2><<<g2, 256, 0, stream>>>(hA, nullptr, nullptr, nullptr, edges, nullptr,
        nullptr, nullptr, scaleB, shiftB, WT1b, nullptr, out_p, pooledF, nullptr,
        nullptr, T, 1152, 512, 0);
    dim3 g3(512 / BN, Ob);
    gemm_k<2, 0><<<g3, 256, 0, stream>>>(nullptr, pooledF, nullptr, nullptr, nullptr,
        invc, nullptr, nullptr, nullptr, nullptr, WT2a, h2, nullptr, nullptr,
        sumC, sqC, O, 512, 512, 0);
  }
  bnfin_k<<<2, 256, 0, stream>>>(sumC, sqC, g2a, be2a, scaleC, shiftC, 512, 1.f / O);

  // GEMM4: bn_lrelu(h2) (O,512) @ W2b -> objpre f32 (in d_out) + statsD
  {
    dim3 g(128 / BN, Ob);
    gemm_k<1, 3><<<g, 256, 0, stream>>>(h2, nullptr, nullptr, nullptr, nullptr, nullptr,
        scaleC, shiftC, nullptr, nullptr, WT2b, nullptr, objpre, nullptr, sumD, sqD,
        O, 128, 512, 0);
  }
  bnfin_k<<<1, 256, 0, stream>>>(sumD, sqD, g2b, be2b, scaleD, shiftD, 128, 1.f / O);

  final_k<<<((size_t)O * 128 + 255) / 256, 256, 0, stream>>>(objpre, scaleD, shiftD,
      (int)((size_t)O * 128));
}